// Round 1
// baseline (258.893 us; speedup 1.0000x reference)
//
#include <hip/hip_runtime.h>
#include <hip/hip_bf16.h>
#include <stdint.h>

#define M_DIM 4096
#define K_DIM 4096
#define N_DIM 4096

typedef __bf16 bf16_t;
typedef __bf16  bf16x8 __attribute__((ext_vector_type(8)));
typedef float   f32x4  __attribute__((ext_vector_type(4)));
typedef float   floatx4 __attribute__((ext_vector_type(4)));

// ---------------- async global->LDS (width 16) ----------------
__device__ __forceinline__ void gload_lds16(const bf16_t* g, bf16_t* l) {
    __builtin_amdgcn_global_load_lds(
        (const __attribute__((address_space(1))) void*)(uintptr_t)g,
        (__attribute__((address_space(3))) void*)(uintptr_t)(unsigned)(uintptr_t)l,
        16, 0, 0);
}

// ---------------- prepass 1: x f32 -> bf16 ----------------
// 16.7M elems, 8 per thread: 32B read / 16B write per thread.
__global__ __launch_bounds__(256) void convert_x(const float* __restrict__ x,
                                                 bf16_t* __restrict__ xb) {
    size_t idx = (size_t)blockIdx.x * blockDim.x + threadIdx.x;
    const floatx4* x4 = (const floatx4*)x;
    floatx4 a = x4[idx * 2];
    floatx4 b = x4[idx * 2 + 1];
    bf16x8 o;
    o[0] = (bf16_t)a[0]; o[1] = (bf16_t)a[1]; o[2] = (bf16_t)a[2]; o[3] = (bf16_t)a[3];
    o[4] = (bf16_t)b[0]; o[5] = (bf16_t)b[1]; o[6] = (bf16_t)b[2]; o[7] = (bf16_t)b[3];
    *(bf16x8*)&xb[idx * 8] = o;
}

// ---------------- prepass 2: w_eff^T = (w_mu + w_sigma*ei*eo)^T as bf16 [N][K] ----------------
// 64x64 tile per block, LDS transpose, padded pitch 65 (f32) -> conflict-free.
__global__ __launch_bounds__(256) void build_wt(const float* __restrict__ w_mu,
                                                const float* __restrict__ w_sigma,
                                                const float* __restrict__ eps_in,
                                                const float* __restrict__ eps_out,
                                                bf16_t* __restrict__ wt) {
    __shared__ float tile[64][65];
    int bk = blockIdx.x & 63;
    int bn = blockIdx.x >> 6;
    int k0 = bk * 64, n0 = bn * 64;
    int t = threadIdx.x;
    int c = t & 63;                 // n-local (coalesced read dim)
    float eo = eps_out[n0 + c];
#pragma unroll
    for (int p = 0; p < 16; ++p) {
        int r = p * 4 + (t >> 6);   // k-local
        int k = k0 + r;
        float ei = eps_in[k];
        size_t off = (size_t)k * N_DIM + n0 + c;
        tile[r][c] = w_mu[off] + w_sigma[off] * (ei * eo);
    }
    __syncthreads();
    // write transposed: wt[n0+rn][k0+ck], 2 bf16 (4B) per thread per pass
#pragma unroll
    for (int p = 0; p < 8; ++p) {
        int rn = p * 8 + (t >> 5);      // n-local
        int ck = (t & 31) * 2;          // k-local
        bf16_t v0 = (bf16_t)tile[ck][rn];
        bf16_t v1 = (bf16_t)tile[ck + 1][rn];
        union { bf16_t b[2]; unsigned u; } u2;
        u2.b[0] = v0; u2.b[1] = v1;
        *(unsigned*)&wt[(size_t)(n0 + rn) * K_DIM + k0 + ck] = u2.u;
    }
}

// ---------------- GEMM: C = relu(A[M,K]·Wt[N,K]^T + bias) ----------------
#define BM 128
#define BN 128
#define BK 64

__global__ __launch_bounds__(256) void gemm_bias_relu(
    const bf16_t* __restrict__ A,    // [M][K] bf16
    const bf16_t* __restrict__ Bt,   // [N][K] bf16
    const float* __restrict__ b_mu,
    const float* __restrict__ b_sigma,
    const float* __restrict__ eps_out,
    float* __restrict__ C) {

    __shared__ __align__(16) bf16_t As[BM * BK];   // 16 KB
    __shared__ __align__(16) bf16_t Bs[BN * BK];   // 16 KB

    // XCD-aware bijective swizzle (1024 blocks % 8 == 0)
    int bid = blockIdx.x;
    int cpx = gridDim.x >> 3;
    int swz = (bid & 7) * cpx + (bid >> 3);
    int tm = swz & 31;
    int tn = swz >> 5;
    int bm = tm * BM, bn = tn * BN;

    int t = threadIdx.x;
    int lane = t & 63;
    int wave = t >> 6;
    int wr = wave >> 1, wc = wave & 1;   // 2x2 wave grid, 64x64 per wave

    f32x4 zero = {0.f, 0.f, 0.f, 0.f};
    f32x4 acc[4][4];
#pragma unroll
    for (int mi = 0; mi < 4; ++mi)
#pragma unroll
        for (int ni = 0; ni < 4; ++ni) acc[mi][ni] = zero;

    // staging: chunk c = p*256 + t, 16B each; row = c/8, col_elem = (c%8)*8
    const bf16_t* aSrc = A  + (size_t)(bm + (t >> 3)) * K_DIM + (t & 7) * 8;
    const bf16_t* bSrc = Bt + (size_t)(bn + (t >> 3)) * K_DIM + (t & 7) * 8;

    int krow = lane & 15;
    int kseg = (lane >> 4) << 3;

    for (int kt = 0; kt < K_DIM / BK; ++kt) {
        __syncthreads();
        const bf16_t* aS = aSrc + kt * BK;
        const bf16_t* bS = bSrc + kt * BK;
#pragma unroll
        for (int p = 0; p < 4; ++p) {
            gload_lds16(aS + (size_t)(p * 32) * K_DIM, &As[(p * 256 + t) * 8]);
            gload_lds16(bS + (size_t)(p * 32) * K_DIM, &Bs[(p * 256 + t) * 8]);
        }
        __syncthreads();
#pragma unroll
        for (int kk = 0; kk < 2; ++kk) {
            int kcol = kk * 32 + kseg;
            bf16x8 a[4], b[4];
#pragma unroll
            for (int mi = 0; mi < 4; ++mi)
                a[mi] = *(const bf16x8*)&As[(wr * 64 + mi * 16 + krow) * BK + kcol];
#pragma unroll
            for (int ni = 0; ni < 4; ++ni)
                b[ni] = *(const bf16x8*)&Bs[(wc * 64 + ni * 16 + krow) * BK + kcol];
#pragma unroll
            for (int mi = 0; mi < 4; ++mi)
#pragma unroll
                for (int ni = 0; ni < 4; ++ni)
                    acc[mi][ni] = __builtin_amdgcn_mfma_f32_16x16x32_bf16(
                        a[mi], b[ni], acc[mi][ni], 0, 0, 0);
        }
    }

    // epilogue: bias + relu, f32 out
    int col0 = lane & 15;
    int row0 = (lane >> 4) * 4;
#pragma unroll
    for (int ni = 0; ni < 4; ++ni) {
        int n = bn + wc * 64 + ni * 16 + col0;
        float bias = b_mu[n] + b_sigma[n] * eps_out[n];
#pragma unroll
        for (int mi = 0; mi < 4; ++mi) {
            int m = bm + wr * 64 + mi * 16 + row0;
#pragma unroll
            for (int r = 0; r < 4; ++r) {
                float v = acc[mi][ni][r] + bias;
                C[(size_t)(m + r) * N_DIM + n] = v > 0.f ? v : 0.f;
            }
        }
    }
}

extern "C" void kernel_launch(void* const* d_in, const int* in_sizes, int n_in,
                              void* d_out, int out_size, void* d_ws, size_t ws_size,
                              hipStream_t stream) {
    const float* x       = (const float*)d_in[0];
    const float* w_mu    = (const float*)d_in[1];
    const float* w_sigma = (const float*)d_in[2];
    const float* b_mu    = (const float*)d_in[3];
    const float* b_sigma = (const float*)d_in[4];
    const float* eps_in  = (const float*)d_in[5];
    const float* eps_out = (const float*)d_in[6];
    float* out = (float*)d_out;

    bf16_t* xb = (bf16_t*)d_ws;                                         // 32 MB
    bf16_t* wt = (bf16_t*)((char*)d_ws + (size_t)M_DIM * K_DIM * 2);    // 32 MB

    convert_x<<<(M_DIM * K_DIM) / (8 * 256), 256, 0, stream>>>(x, xb);
    build_wt<<<64 * 64, 256, 0, stream>>>(w_mu, w_sigma, eps_in, eps_out, wt);
    gemm_bias_relu<<<(M_DIM / BM) * (N_DIM / BN), 256, 0, stream>>>(
        xb, wt, b_mu, b_sigma, eps_out, out);
}

// Round 2
// 170.697 us; speedup vs baseline: 1.5167x; 1.5167x over previous
//
#include <hip/hip_runtime.h>
#include <hip/hip_bf16.h>
#include <stdint.h>

#define M_DIM 4096
#define K_DIM 4096
#define N_DIM 4096

typedef __bf16 bf16_t;
typedef __bf16  bf16x8 __attribute__((ext_vector_type(8)));
typedef float   f32x4  __attribute__((ext_vector_type(4)));
typedef float   floatx4 __attribute__((ext_vector_type(4)));

// ---------------- async global->LDS (width 16) ----------------
__device__ __forceinline__ void gload_lds16(const bf16_t* g, bf16_t* l) {
    __builtin_amdgcn_global_load_lds(
        (const __attribute__((address_space(1))) void*)(uintptr_t)g,
        (__attribute__((address_space(3))) void*)(uintptr_t)(unsigned)(uintptr_t)l,
        16, 0, 0);
}

// ---------------- prepass 1: x f32 -> bf16 ----------------
__global__ __launch_bounds__(256) void convert_x(const float* __restrict__ x,
                                                 bf16_t* __restrict__ xb) {
    size_t idx = (size_t)blockIdx.x * blockDim.x + threadIdx.x;
    const floatx4* x4 = (const floatx4*)x;
    floatx4 a = x4[idx * 2];
    floatx4 b = x4[idx * 2 + 1];
    bf16x8 o;
    o[0] = (bf16_t)a[0]; o[1] = (bf16_t)a[1]; o[2] = (bf16_t)a[2]; o[3] = (bf16_t)a[3];
    o[4] = (bf16_t)b[0]; o[5] = (bf16_t)b[1]; o[6] = (bf16_t)b[2]; o[7] = (bf16_t)b[3];
    *(bf16x8*)&xb[idx * 8] = o;
}

// ---------------- prepass 2: w_eff^T bf16 [N][K] ----------------
__global__ __launch_bounds__(256) void build_wt(const float* __restrict__ w_mu,
                                                const float* __restrict__ w_sigma,
                                                const float* __restrict__ eps_in,
                                                const float* __restrict__ eps_out,
                                                bf16_t* __restrict__ wt) {
    __shared__ float tile[64][65];
    int bk = blockIdx.x & 63;
    int bn = blockIdx.x >> 6;
    int k0 = bk * 64, n0 = bn * 64;
    int t = threadIdx.x;
    int c = t & 63;
    float eo = eps_out[n0 + c];
#pragma unroll
    for (int p = 0; p < 16; ++p) {
        int r = p * 4 + (t >> 6);
        int k = k0 + r;
        float ei = eps_in[k];
        size_t off = (size_t)k * N_DIM + n0 + c;
        tile[r][c] = w_mu[off] + w_sigma[off] * (ei * eo);
    }
    __syncthreads();
#pragma unroll
    for (int p = 0; p < 8; ++p) {
        int rn = p * 8 + (t >> 5);
        int ck = (t & 31) * 2;
        bf16_t v0 = (bf16_t)tile[ck][rn];
        bf16_t v1 = (bf16_t)tile[ck + 1][rn];
        union { bf16_t b[2]; unsigned u; } u2;
        u2.b[0] = v0; u2.b[1] = v1;
        *(unsigned*)&wt[(size_t)(n0 + rn) * K_DIM + k0 + ck] = u2.u;
    }
}

// ---------------- 256x256 8-phase GEMM: C = relu(A·Bt^T + bias) ----------------
#define BM 256
#define BN 256
#define BK 64
#define NT (K_DIM / BK)

// stage one half-tile (128 rows x 64 cols bf16 = 16KB): 2 x gload_lds16/thread.
// LDS dest linear; global source column pre-swizzled (XOR involution, rule #21).
__device__ __forceinline__ void stage_half(bf16_t* lds, const bf16_t* g, int kcol0, int t) {
#pragma unroll
    for (int p = 0; p < 2; ++p) {
        int chunk = p * 512 + t;
        int row = chunk >> 3;
        int c16 = chunk & 7;
        gload_lds16(g + (size_t)row * K_DIM + kcol0 + ((c16 ^ (row & 7)) << 3),
                    lds + row * BK + (c16 << 3));
    }
}

// swizzled ds_read of one bf16x8 fragment
__device__ __forceinline__ bf16x8 lds_frag(const bf16_t* base, int row, int kcol) {
    int c16 = kcol >> 3;
    return *(const bf16x8*)(base + row * BK + (((c16 ^ (row & 7)) << 3)));
}

#define BAR()  asm volatile("s_barrier" ::: "memory")

__global__ __launch_bounds__(512, 2) void gemm8p(
    const bf16_t* __restrict__ A,    // [M][K] bf16
    const bf16_t* __restrict__ Bt,   // [N][K] bf16
    const float* __restrict__ b_mu,
    const float* __restrict__ b_sigma,
    const float* __restrict__ eps_out,
    float* __restrict__ C) {

    __shared__ __align__(16) bf16_t As[2][BM * BK];   // 2 x 32 KB
    __shared__ __align__(16) bf16_t Bs[2][BN * BK];   // 2 x 32 KB

    // XCD-aware bijective swizzle (256 blocks % 8 == 0)
    int bid = blockIdx.x;
    int swz = (bid & 7) * (gridDim.x >> 3) + (bid >> 3);
    int tm = swz & 15, tn = swz >> 4;
    size_t bm = (size_t)tm * BM, bn = (size_t)tn * BN;

    int t = threadIdx.x;
    int lane = t & 63;
    int wave = t >> 6;
    int wr = wave >> 2, wc = wave & 3;   // 2(M) x 4(N) waves; per-wave out 128x64
    int l15 = lane & 15;
    int kseg = (lane >> 4) << 3;

    const bf16_t* Ab = A  + bm * (size_t)K_DIM;
    const bf16_t* Bb = Bt + bn * (size_t)K_DIM;

    f32x4 zero = {0.f, 0.f, 0.f, 0.f};
    f32x4 acc[8][4];
#pragma unroll
    for (int i = 0; i < 8; ++i)
#pragma unroll
        for (int j = 0; j < 4; ++j) acc[i][j] = zero;

    // ---- prologue: T0 {A0,A1,B0,B1} + T1.A0 ; vmcnt(2) -> T0 landed ----
    stage_half(&As[0][0],            Ab,                        0, t);
    stage_half(&As[0][128 * BK],     Ab + (size_t)128 * K_DIM,  0, t);
    stage_half(&Bs[0][0],            Bb,                        0, t);
    stage_half(&Bs[0][128 * BK],     Bb + (size_t)128 * K_DIM,  0, t);
    stage_half(&As[1][0],            Ab,                        BK, t);
    asm volatile("s_waitcnt vmcnt(2)" ::: "memory");
    BAR();

    for (int kt = 0; kt < NT; ++kt) {
        const int cur = kt & 1, nxt = cur ^ 1;
        const bf16_t* As_c = &As[cur][0];
        const bf16_t* Bs_c = &Bs[cur][0];
        const int kb1 = (kt + 1) * BK;
        const int kb2 = (kt + 2) * BK;
        const bool st1 = (kt + 1 < NT);
        bf16x8 af[4][2], bq0[2][2], bq1[2][2];

        // ======== P1: read A(qm0)+B(qn0); stage T(kt+1).A1; MFMA Q(0,0) ========
#pragma unroll
        for (int mi = 0; mi < 4; ++mi)
#pragma unroll
            for (int kk = 0; kk < 2; ++kk)
                af[mi][kk] = lds_frag(As_c, wr * 128 + mi * 16 + l15, kk * 32 + kseg);
#pragma unroll
        for (int ni = 0; ni < 2; ++ni)
#pragma unroll
            for (int kk = 0; kk < 2; ++kk)
                bq0[ni][kk] = lds_frag(Bs_c, wc * 64 + ni * 16 + l15, kk * 32 + kseg);
        if (st1) stage_half(&As[nxt][128 * BK], Ab + (size_t)128 * K_DIM, kb1, t);
        BAR();
        __builtin_amdgcn_s_setprio(1);
#pragma unroll
        for (int mi = 0; mi < 4; ++mi)
#pragma unroll
            for (int ni = 0; ni < 2; ++ni)
#pragma unroll
                for (int kk = 0; kk < 2; ++kk)
                    acc[mi][ni] = __builtin_amdgcn_mfma_f32_16x16x32_bf16(
                        af[mi][kk], bq0[ni][kk], acc[mi][ni], 0, 0, 0);
        __builtin_amdgcn_s_setprio(0);
        BAR();

        // ======== P2: read B(qn1); stage T(kt+1).B0; MFMA Q(0,1) ========
#pragma unroll
        for (int ni = 0; ni < 2; ++ni)
#pragma unroll
            for (int kk = 0; kk < 2; ++kk)
                bq1[ni][kk] = lds_frag(Bs_c, wc * 64 + 32 + ni * 16 + l15, kk * 32 + kseg);
        if (st1) stage_half(&Bs[nxt][0], Bb, kb1, t);
        BAR();
        __builtin_amdgcn_s_setprio(1);
#pragma unroll
        for (int mi = 0; mi < 4; ++mi)
#pragma unroll
            for (int ni = 0; ni < 2; ++ni)
#pragma unroll
                for (int kk = 0; kk < 2; ++kk)
                    acc[mi][2 + ni] = __builtin_amdgcn_mfma_f32_16x16x32_bf16(
                        af[mi][kk], bq1[ni][kk], acc[mi][2 + ni], 0, 0, 0);
        __builtin_amdgcn_s_setprio(0);
        BAR();

        // ======== P3: read A(qm1); stage T(kt+1).B1; MFMA Q(1,1) ========
#pragma unroll
        for (int mi = 0; mi < 4; ++mi)
#pragma unroll
            for (int kk = 0; kk < 2; ++kk)
                af[mi][kk] = lds_frag(As_c, wr * 128 + 64 + mi * 16 + l15, kk * 32 + kseg);
        if (st1) stage_half(&Bs[nxt][128 * BK], Bb + (size_t)128 * K_DIM, kb1, t);
        BAR();
        __builtin_amdgcn_s_setprio(1);
#pragma unroll
        for (int mi = 0; mi < 4; ++mi)
#pragma unroll
            for (int ni = 0; ni < 2; ++ni)
#pragma unroll
                for (int kk = 0; kk < 2; ++kk)
                    acc[4 + mi][2 + ni] = __builtin_amdgcn_mfma_f32_16x16x32_bf16(
                        af[mi][kk], bq1[ni][kk], acc[4 + mi][2 + ni], 0, 0, 0);
        __builtin_amdgcn_s_setprio(0);
        BAR();

        // ======== P4: stage T(kt+2).A0; MFMA Q(1,0); counted vmcnt ========
        if (kt + 2 < NT) stage_half(&As[cur][0], Ab, kb2, t);
        BAR();
        __builtin_amdgcn_s_setprio(1);
#pragma unroll
        for (int mi = 0; mi < 4; ++mi)
#pragma unroll
            for (int ni = 0; ni < 2; ++ni)
#pragma unroll
                for (int kk = 0; kk < 2; ++kk)
                    acc[4 + mi][ni] = __builtin_amdgcn_mfma_f32_16x16x32_bf16(
                        af[mi][kk], bq0[ni][kk], acc[4 + mi][ni], 0, 0, 0);
        __builtin_amdgcn_s_setprio(0);
        if (kt < NT - 2) {
            asm volatile("s_waitcnt vmcnt(2)" ::: "memory");   // T(kt+1) fully landed
        } else if (kt == NT - 2) {
            asm volatile("s_waitcnt vmcnt(0)" ::: "memory");   // epilogue drain
        }
        BAR();
    }

    // ---- epilogue: bias + relu, f32 out ----
    int col0 = l15;
    int row0 = (lane >> 4) * 4;
#pragma unroll
    for (int qn = 0; qn < 2; ++qn)
#pragma unroll
        for (int ni = 0; ni < 2; ++ni) {
            int n = (int)bn + wc * 64 + qn * 32 + ni * 16 + col0;
            float bias = b_mu[n] + b_sigma[n] * eps_out[n];
#pragma unroll
            for (int qm = 0; qm < 2; ++qm)
#pragma unroll
                for (int mi = 0; mi < 4; ++mi) {
                    int m = (int)bm + wr * 128 + qm * 64 + mi * 16 + row0;
                    f32x4 v = acc[qm * 4 + mi][qn * 2 + ni];
#pragma unroll
                    for (int r = 0; r < 4; ++r) {
                        float o = v[r] + bias;
                        C[(size_t)(m + r) * N_DIM + n] = o > 0.f ? o : 0.f;
                    }
                }
        }
}

extern "C" void kernel_launch(void* const* d_in, const int* in_sizes, int n_in,
                              void* d_out, int out_size, void* d_ws, size_t ws_size,
                              hipStream_t stream) {
    const float* x       = (const float*)d_in[0];
    const float* w_mu    = (const float*)d_in[1];
    const float* w_sigma = (const float*)d_in[2];
    const float* b_mu    = (const float*)d_in[3];
    const float* b_sigma = (const float*)d_in[4];
    const float* eps_in  = (const float*)d_in[5];
    const float* eps_out = (const float*)d_in[6];
    float* out = (float*)d_out;

    bf16_t* xb = (bf16_t*)d_ws;                                         // 32 MB
    bf16_t* wt = (bf16_t*)((char*)d_ws + (size_t)M_DIM * K_DIM * 2);    // 32 MB

    convert_x<<<(M_DIM * K_DIM) / (8 * 256), 256, 0, stream>>>(x, xb);
    build_wt<<<64 * 64, 256, 0, stream>>>(w_mu, w_sigma, eps_in, eps_out, wt);
    gemm8p<<<(M_DIM / BM) * (N_DIM / BN), 512, 0, stream>>>(
        xb, wt, b_mu, b_sigma, eps_out, out);
}